// Round 1
// baseline (3446.351 us; speedup 1.0000x reference)
//
#include <hip/hip_runtime.h>
#include <math.h>
#include <float.h>

#define NG 64
#define GDIM 128

// ---------------- degree / dinv ----------------
__global__ void deg_init_kernel(float* deg, int n) {
    int i = blockIdx.x * blockDim.x + threadIdx.x;
    if (i < n) deg[i] = 1.0f;   // self-loop contributes 1
}

__global__ void deg_count_kernel(const int* __restrict__ col, float* deg, int E) {
    int i = blockIdx.x * blockDim.x + threadIdx.x;
    if (i < E) atomicAdd(&deg[col[i]], 1.0f);
}

__global__ void dinv_kernel(float* deg, int n) {
    int i = blockIdx.x * blockDim.x + threadIdx.x;
    if (i < n) deg[i] = rsqrtf(deg[i]);   // deg >= 1 always
}

// ---------------- glob init ----------------
__global__ void glob_tile_kernel(const float* __restrict__ gi, float* glob) {
    glob[blockIdx.x * GDIM + threadIdx.x] = gi[threadIdx.x];
}

// ---------------- gn = glob @ Wgn + bgn  [NG, dout] ----------------
__global__ void gn_kernel(const float* __restrict__ glob, const float* __restrict__ Wgn,
                          const float* __restrict__ bgn, float* __restrict__ gn, int dout) {
    int g = blockIdx.x, j = threadIdx.x;
    float s = bgn[j];
    const float* gr = glob + g * GDIM;
    for (int k = 0; k < GDIM; ++k) s = fmaf(gr[k], Wgn[k * dout + j], s);
    gn[g * dout + j] = s;
}

// ---------------- node GEMM: C = relu?(A) @ W + bnn + gn[ga] ----------------
// A [N,K] row-major, W [K,DOUT] row-major, BM=BN=64, BK=32, 256 thr, 4x4/thread
__global__ __launch_bounds__(256) void gemm_kernel(
    const float* __restrict__ A, const float* __restrict__ W,
    const float* __restrict__ bias, const float* __restrict__ gn,
    const int* __restrict__ ga, float* __restrict__ C,
    int N, int K, int DOUT, int relu)
{
    constexpr int BM = 64, BN = 64, BK = 32, AST = 68;  // AST pad: staging-store conflicts -> ~4-way
    __shared__ float As[BK * AST];  // transposed [k][m]
    __shared__ float Ws[BK * BN];   // [k][n]
    int tid = threadIdx.x;
    int row0 = blockIdx.x * BM;
    int col0 = blockIdx.y * BN;
    int tr = tid >> 4, tc = tid & 15;
    float acc[4][4] = {};

    for (int k0 = 0; k0 < K; k0 += BK) {
        #pragma unroll
        for (int it = 0; it < 2; ++it) {
            int slot = tid + it * 256;         // 512 float4 slots
            int ar = slot >> 3, ak = (slot & 7) << 2;
            int grow = row0 + ar;
            float4 v = make_float4(0.f, 0.f, 0.f, 0.f);
            if (grow < N) v = *(const float4*)(A + (size_t)grow * K + k0 + ak);
            if (relu) {
                v.x = fmaxf(v.x, 0.f); v.y = fmaxf(v.y, 0.f);
                v.z = fmaxf(v.z, 0.f); v.w = fmaxf(v.w, 0.f);
            }
            As[(ak + 0) * AST + ar] = v.x;
            As[(ak + 1) * AST + ar] = v.y;
            As[(ak + 2) * AST + ar] = v.z;
            As[(ak + 3) * AST + ar] = v.w;
        }
        #pragma unroll
        for (int it = 0; it < 2; ++it) {
            int slot = tid + it * 256;
            int wk = slot >> 4, wn = (slot & 15) << 2;
            float4 w = *(const float4*)(W + (size_t)(k0 + wk) * DOUT + col0 + wn);
            *(float4*)(Ws + wk * BN + wn) = w;
        }
        __syncthreads();
        #pragma unroll
        for (int k = 0; k < BK; ++k) {
            float4 a = *(const float4*)(As + k * AST + tr * 4);
            float4 b = *(const float4*)(Ws + k * BN + tc * 4);
            float av[4] = {a.x, a.y, a.z, a.w};
            float bv[4] = {b.x, b.y, b.z, b.w};
            #pragma unroll
            for (int i = 0; i < 4; ++i)
                #pragma unroll
                for (int j = 0; j < 4; ++j)
                    acc[i][j] = fmaf(av[i], bv[j], acc[i][j]);
        }
        __syncthreads();
    }

    float4 bb = *(const float4*)(bias + col0 + tc * 4);
    #pragma unroll
    for (int i = 0; i < 4; ++i) {
        int r = row0 + tr * 4 + i;
        if (r < N) {
            int g = ga[r];
            float4 gg = *(const float4*)(gn + (size_t)g * DOUT + col0 + tc * 4);
            float4 o;
            o.x = acc[i][0] + bb.x + gg.x;
            o.y = acc[i][1] + bb.y + gg.y;
            o.z = acc[i][2] + bb.z + gg.z;
            o.w = acc[i][3] + bb.w + gg.w;
            *(float4*)(C + (size_t)r * DOUT + col0 + tc * 4) = o;
        }
    }
}

// ---------------- self-loop init: h[i] = dinv[i]^2 * tmp[i] ----------------
template <int DOUT>
__global__ void selfloop_kernel(const float* __restrict__ tmp, const float* __restrict__ dinv,
                                float* __restrict__ h, int n) {
    constexpr int Q = DOUT / 4;
    int idx = blockIdx.x * blockDim.x + threadIdx.x;
    int i = idx / Q, q = idx % Q;
    if (i >= n) return;
    float d = dinv[i];
    float s = d * d;
    float4 v = *(const float4*)(tmp + (size_t)i * DOUT + q * 4);
    float4 o = make_float4(s * v.x, s * v.y, s * v.z, s * v.w);
    *(float4*)(h + (size_t)i * DOUT + q * 4) = o;
}

// ---------------- edge scatter: h[col] += dinv[r]*dinv[c]*tmp[row] ----------------
template <int DOUT>
__global__ void scatter_kernel(const float* __restrict__ tmp, float* __restrict__ h,
                               const int* __restrict__ row, const int* __restrict__ col,
                               const float* __restrict__ dinv, int E) {
    constexpr int TPE = DOUT / 4;
    int t = blockIdx.x * blockDim.x + threadIdx.x;
    int e = t / TPE;
    if (e >= E) return;
    int lane = t % TPE;
    int r = row[e], c = col[e];
    float nrm = dinv[r] * dinv[c];
    float4 v = *(const float4*)(tmp + (size_t)r * DOUT + lane * 4);
    float* dst = h + (size_t)c * DOUT + lane * 4;
    atomicAdd(dst + 0, nrm * v.x);
    atomicAdd(dst + 1, nrm * v.y);
    atomicAdd(dst + 2, nrm * v.z);
    atomicAdd(dst + 3, nrm * v.w);
}

// ---------------- per-graph max, chunked (ga is sorted) ----------------
__global__ void parts_partial_kernel(const float* __restrict__ h, const int* __restrict__ ga,
                                     float* __restrict__ pp, int n, int dout) {
    int g = blockIdx.x, ch = blockIdx.y, nch = gridDim.y;
    int lo = 0, hi = n;
    while (lo < hi) { int m = (lo + hi) >> 1; if (ga[m] < g) lo = m + 1; else hi = m; }
    int s = lo;
    lo = s; hi = n;
    while (lo < hi) { int m = (lo + hi) >> 1; if (ga[m] <= g) lo = m + 1; else hi = m; }
    int epos = lo;
    int cnt = epos - s;
    int per = (cnt + nch - 1) / nch;
    int a = s + ch * per;
    int b = min(epos, a + per);
    for (int j = threadIdx.x; j < dout; j += blockDim.x) {
        float m = -INFINITY;
        for (int i = a; i < b; ++i) m = fmaxf(m, h[(size_t)i * dout + j]);
        pp[((size_t)g * nch + ch) * dout + j] = m;
    }
}

__global__ void parts_reduce_kernel(const float* __restrict__ pp, float* __restrict__ parts,
                                    int dout, int nch) {
    int g = blockIdx.x, j = threadIdx.x;
    float m = -INFINITY;
    for (int c = 0; c < nch; ++c) m = fmaxf(m, pp[((size_t)g * nch + c) * dout + j]);
    parts[g * dout + j] = m;
}

// ---------------- glob update: glob@Wgg + bgg + parts@Wng + bng ----------------
__global__ void glob_update_kernel(const float* __restrict__ glob, const float* __restrict__ Wgg,
                                   const float* __restrict__ bgg, const float* __restrict__ parts,
                                   const float* __restrict__ Wng, const float* __restrict__ bng,
                                   float* __restrict__ out, int dout) {
    int g = blockIdx.x, j = threadIdx.x;
    float s = bgg[j] + bng[j];
    const float* gr = glob + g * GDIM;
    for (int k = 0; k < GDIM; ++k) s = fmaf(gr[k], Wgg[k * GDIM + j], s);
    const float* pr = parts + (size_t)g * dout;
    for (int k = 0; k < dout; ++k) s = fmaf(pr[k], Wng[k * GDIM + j], s);
    out[g * GDIM + j] = s;
}

// ---------------- final sigmoid ----------------
__global__ void sigmoid_kernel(const float* __restrict__ h, float* __restrict__ out, int total4) {
    int idx = blockIdx.x * blockDim.x + threadIdx.x;
    if (idx >= total4) return;
    float4 v = *(const float4*)(h + (size_t)idx * 4);
    float4 o;
    o.x = 1.0f / (1.0f + expf(-v.x));
    o.y = 1.0f / (1.0f + expf(-v.y));
    o.z = 1.0f / (1.0f + expf(-v.z));
    o.w = 1.0f / (1.0f + expf(-v.w));
    *(float4*)(out + (size_t)idx * 4) = o;
}

extern "C" void kernel_launch(void* const* d_in, const int* in_sizes, int n_in,
                              void* d_out, int out_size, void* d_ws, size_t ws_size,
                              hipStream_t stream) {
    const float* x         = (const float*)d_in[0];
    const int*   ei        = (const int*)d_in[1];
    const int*   ga        = (const int*)d_in[2];
    const float* glob_init = (const float*)d_in[3];

    const int n = in_sizes[0] / 128;   // 50000
    const int E = in_sizes[1] / 2;     // 400000
    const int* row = ei;               // sources
    const int* col = ei + E;           // targets

    float* ws = (float*)d_ws;
    size_t off = 0;
    auto alloc = [&](size_t cnt) { float* p = ws + off; off += cnt; return p; };
    float* tmp   = alloc((size_t)n * 256);
    float* hbuf  = alloc((size_t)n * 256);
    float* dinv  = alloc((size_t)n);
    float* gn    = alloc((size_t)NG * 256);
    float* pp    = alloc((size_t)NG * 16 * 256);
    float* parts = alloc((size_t)NG * 256);
    float* globA = alloc((size_t)NG * GDIM);
    float* globB = alloc((size_t)NG * GDIM);
    (void)ws_size; (void)n_in; (void)out_size;

    deg_init_kernel<<<(n + 255) / 256, 256, 0, stream>>>(dinv, n);
    deg_count_kernel<<<(E + 255) / 256, 256, 0, stream>>>(col, dinv, E);
    dinv_kernel<<<(n + 255) / 256, 256, 0, stream>>>(dinv, n);
    glob_tile_kernel<<<NG, GDIM, 0, stream>>>(glob_init, globA);

    const float* hin = x;
    float* gcur = globA;
    float* gnext = globB;
    int K = 128;
    for (int li = 0; li < 3; ++li) {
        const float* Wnn = (const float*)d_in[4 + li * 8 + 0];
        const float* bnn = (const float*)d_in[4 + li * 8 + 1];
        const float* Wgn = (const float*)d_in[4 + li * 8 + 2];
        const float* bgn = (const float*)d_in[4 + li * 8 + 3];
        const float* Wgg = (const float*)d_in[4 + li * 8 + 4];
        const float* bgg = (const float*)d_in[4 + li * 8 + 5];
        const float* Wng = (const float*)d_in[4 + li * 8 + 6];
        const float* bng = (const float*)d_in[4 + li * 8 + 7];
        const int dout = (li == 2) ? 64 : 256;

        gn_kernel<<<NG, dout, 0, stream>>>(gcur, Wgn, bgn, gn, dout);

        dim3 ggrid((n + 63) / 64, dout / 64);
        gemm_kernel<<<ggrid, 256, 0, stream>>>(hin, Wnn, bnn, gn, ga, tmp, n, K, dout,
                                               li > 0 ? 1 : 0);

        if (dout == 256) {
            selfloop_kernel<256><<<((size_t)n * 64 + 255) / 256, 256, 0, stream>>>(tmp, dinv, hbuf, n);
            scatter_kernel<256><<<((size_t)E * 64 + 255) / 256, 256, 0, stream>>>(tmp, hbuf, row, col, dinv, E);
        } else {
            selfloop_kernel<64><<<((size_t)n * 16 + 255) / 256, 256, 0, stream>>>(tmp, dinv, hbuf, n);
            scatter_kernel<64><<<((size_t)E * 16 + 255) / 256, 256, 0, stream>>>(tmp, hbuf, row, col, dinv, E);
        }

        if (li < 2) {   // layer-2 glob update is dead code w.r.t. the output
            dim3 pgrid(NG, 16);
            parts_partial_kernel<<<pgrid, 256, 0, stream>>>(hbuf, ga, pp, n, dout);
            parts_reduce_kernel<<<NG, dout, 0, stream>>>(pp, parts, dout, 16);
            glob_update_kernel<<<NG, GDIM, 0, stream>>>(gcur, Wgg, bgg, parts, Wng, bng, gnext, dout);
            float* t = gcur; gcur = gnext; gnext = t;
        }
        hin = hbuf;
        K = dout;
    }

    sigmoid_kernel<<<((size_t)n * 64 / 4 + 255) / 256, 256, 0, stream>>>(hbuf, (float*)d_out,
                                                                         n * 64 / 4);
}

// Round 2
// 687.452 us; speedup vs baseline: 5.0132x; 5.0132x over previous
//
#include <hip/hip_runtime.h>
#include <math.h>
#include <float.h>

#define NG 64
#define GDIM 128

// ---------------- int zero ----------------
__global__ void zero_int_kernel(int* p, int n) {
    int i = blockIdx.x * blockDim.x + threadIdx.x;
    if (i < n) p[i] = 0;
}

// ---------------- in-degree histogram (excluding self-loop) ----------------
__global__ void count_kernel(const int* __restrict__ col, int* cnt, int E) {
    int i = blockIdx.x * blockDim.x + threadIdx.x;
    if (i < E) atomicAdd(&cnt[col[i]], 1);
}

// ---------------- dinv from counts (+1 self loop) ----------------
__global__ void dinv_kernel(const int* __restrict__ cnt, float* dinv, int n) {
    int i = blockIdx.x * blockDim.x + threadIdx.x;
    if (i < n) dinv[i] = rsqrtf((float)cnt[i] + 1.0f);
}

// ---------------- single-block exclusive scan: start[0..n] ----------------
__global__ __launch_bounds__(1024) void scan_kernel(const int* __restrict__ cnt,
                                                    int* __restrict__ start, int n) {
    __shared__ int buf[1024];
    int carry = 0;
    for (int base = 0; base < n; base += 1024) {
        int i = base + threadIdx.x;
        int v = (i < n) ? cnt[i] : 0;
        buf[threadIdx.x] = v;
        __syncthreads();
        #pragma unroll
        for (int off = 1; off < 1024; off <<= 1) {
            int t = (threadIdx.x >= off) ? buf[threadIdx.x - off] : 0;
            __syncthreads();
            buf[threadIdx.x] += t;
            __syncthreads();
        }
        if (i < n) start[i + 1] = carry + buf[threadIdx.x];
        carry += buf[1023];
        __syncthreads();
    }
    if (threadIdx.x == 0) start[0] = 0;
}

__global__ void copy_int_kernel(const int* __restrict__ a, int* b, int n) {
    int i = blockIdx.x * blockDim.x + threadIdx.x;
    if (i < n) b[i] = a[i];
}

// ---------------- bucket fill: esrc sorted by destination ----------------
__global__ void fill_kernel(const int* __restrict__ row, const int* __restrict__ col,
                            int* cursor, int* __restrict__ esrc, int E) {
    int e = blockIdx.x * blockDim.x + threadIdx.x;
    if (e >= E) return;
    int c = col[e];
    int p = atomicAdd(&cursor[c], 1);
    esrc[p] = row[e];
}

// ---------------- glob init ----------------
__global__ void glob_tile_kernel(const float* __restrict__ gi, float* glob) {
    glob[blockIdx.x * GDIM + threadIdx.x] = gi[threadIdx.x];
}

// ---------------- gn = glob @ Wgn + bgn  [NG, dout] ----------------
__global__ void gn_kernel(const float* __restrict__ glob, const float* __restrict__ Wgn,
                          const float* __restrict__ bgn, float* __restrict__ gn, int dout) {
    int g = blockIdx.x, j = threadIdx.x;
    float s = bgn[j];
    const float* gr = glob + g * GDIM;
    for (int k = 0; k < GDIM; ++k) s = fmaf(gr[k], Wgn[k * dout + j], s);
    gn[g * dout + j] = s;
}

// ---------------- node GEMM: C = relu?(A) @ W + bnn + gn[ga] ----------------
__global__ __launch_bounds__(256) void gemm_kernel(
    const float* __restrict__ A, const float* __restrict__ W,
    const float* __restrict__ bias, const float* __restrict__ gn,
    const int* __restrict__ ga, float* __restrict__ C,
    int N, int K, int DOUT, int relu)
{
    constexpr int BM = 64, BN = 64, BK = 32, AST = 68;
    __shared__ float As[BK * AST];  // transposed [k][m]
    __shared__ float Ws[BK * BN];   // [k][n]
    int tid = threadIdx.x;
    int row0 = blockIdx.x * BM;
    int col0 = blockIdx.y * BN;
    int tr = tid >> 4, tc = tid & 15;
    float acc[4][4] = {};

    for (int k0 = 0; k0 < K; k0 += BK) {
        #pragma unroll
        for (int it = 0; it < 2; ++it) {
            int slot = tid + it * 256;
            int ar = slot >> 3, ak = (slot & 7) << 2;
            int grow = row0 + ar;
            float4 v = make_float4(0.f, 0.f, 0.f, 0.f);
            if (grow < N) v = *(const float4*)(A + (size_t)grow * K + k0 + ak);
            if (relu) {
                v.x = fmaxf(v.x, 0.f); v.y = fmaxf(v.y, 0.f);
                v.z = fmaxf(v.z, 0.f); v.w = fmaxf(v.w, 0.f);
            }
            As[(ak + 0) * AST + ar] = v.x;
            As[(ak + 1) * AST + ar] = v.y;
            As[(ak + 2) * AST + ar] = v.z;
            As[(ak + 3) * AST + ar] = v.w;
        }
        #pragma unroll
        for (int it = 0; it < 2; ++it) {
            int slot = tid + it * 256;
            int wk = slot >> 4, wn = (slot & 15) << 2;
            float4 w = *(const float4*)(W + (size_t)(k0 + wk) * DOUT + col0 + wn);
            *(float4*)(Ws + wk * BN + wn) = w;
        }
        __syncthreads();
        #pragma unroll
        for (int k = 0; k < BK; ++k) {
            float4 a = *(const float4*)(As + k * AST + tr * 4);
            float4 b = *(const float4*)(Ws + k * BN + tc * 4);
            float av[4] = {a.x, a.y, a.z, a.w};
            float bv[4] = {b.x, b.y, b.z, b.w};
            #pragma unroll
            for (int i = 0; i < 4; ++i)
                #pragma unroll
                for (int j = 0; j < 4; ++j)
                    acc[i][j] = fmaf(av[i], bv[j], acc[i][j]);
        }
        __syncthreads();
    }

    float4 bb = *(const float4*)(bias + col0 + tc * 4);
    #pragma unroll
    for (int i = 0; i < 4; ++i) {
        int r = row0 + tr * 4 + i;
        if (r < N) {
            int g = ga[r];
            float4 gg = *(const float4*)(gn + (size_t)g * DOUT + col0 + tc * 4);
            float4 o;
            o.x = acc[i][0] + bb.x + gg.x;
            o.y = acc[i][1] + bb.y + gg.y;
            o.z = acc[i][2] + bb.z + gg.z;
            o.w = acc[i][3] + bb.w + gg.w;
            *(float4*)(C + (size_t)r * DOUT + col0 + tc * 4) = o;
        }
    }
}

// ---------------- CSR gather: h[i] = dinv[i]^2*tmp[i] + sum_e dinv[i]*dinv[r]*tmp[r] ----------------
template <int DOUT>
__global__ void gather_kernel(const float* __restrict__ tmp, float* __restrict__ h,
                              const int* __restrict__ start, const int* __restrict__ esrc,
                              const float* __restrict__ dinv, int n) {
    constexpr int LPN = DOUT / 4;   // lanes per node
    int t = blockIdx.x * blockDim.x + threadIdx.x;
    int node = t / LPN;
    if (node >= n) return;
    int lane = t % LPN;
    float dc = dinv[node];
    const float* src0 = tmp + (size_t)node * DOUT + lane * 4;
    float4 v = *(const float4*)src0;
    float s0 = dc * dc;
    float ax = s0 * v.x, ay = s0 * v.y, az = s0 * v.z, aw = s0 * v.w;
    int a = start[node], b = start[node + 1];
    for (int j = a; j < b; ++j) {
        int r = esrc[j];
        float nrm = dc * dinv[r];
        float4 u = *(const float4*)(tmp + (size_t)r * DOUT + lane * 4);
        ax = fmaf(nrm, u.x, ax);
        ay = fmaf(nrm, u.y, ay);
        az = fmaf(nrm, u.z, az);
        aw = fmaf(nrm, u.w, aw);
    }
    *(float4*)(h + (size_t)node * DOUT + lane * 4) = make_float4(ax, ay, az, aw);
}

// ---------------- per-graph max, chunked (ga is sorted) ----------------
__global__ void parts_partial_kernel(const float* __restrict__ h, const int* __restrict__ ga,
                                     float* __restrict__ pp, int n, int dout) {
    int g = blockIdx.x, ch = blockIdx.y, nch = gridDim.y;
    int lo = 0, hi = n;
    while (lo < hi) { int m = (lo + hi) >> 1; if (ga[m] < g) lo = m + 1; else hi = m; }
    int s = lo;
    lo = s; hi = n;
    while (lo < hi) { int m = (lo + hi) >> 1; if (ga[m] <= g) lo = m + 1; else hi = m; }
    int epos = lo;
    int cnt = epos - s;
    int per = (cnt + nch - 1) / nch;
    int a = s + ch * per;
    int b = min(epos, a + per);
    for (int j = threadIdx.x; j < dout; j += blockDim.x) {
        float m = -INFINITY;
        for (int i = a; i < b; ++i) m = fmaxf(m, h[(size_t)i * dout + j]);
        pp[((size_t)g * nch + ch) * dout + j] = m;
    }
}

__global__ void parts_reduce_kernel(const float* __restrict__ pp, float* __restrict__ parts,
                                    int dout, int nch) {
    int g = blockIdx.x, j = threadIdx.x;
    float m = -INFINITY;
    for (int c = 0; c < nch; ++c) m = fmaxf(m, pp[((size_t)g * nch + c) * dout + j]);
    parts[g * dout + j] = m;
}

// ---------------- glob update ----------------
__global__ void glob_update_kernel(const float* __restrict__ glob, const float* __restrict__ Wgg,
                                   const float* __restrict__ bgg, const float* __restrict__ parts,
                                   const float* __restrict__ Wng, const float* __restrict__ bng,
                                   float* __restrict__ out, int dout) {
    int g = blockIdx.x, j = threadIdx.x;
    float s = bgg[j] + bng[j];
    const float* gr = glob + g * GDIM;
    for (int k = 0; k < GDIM; ++k) s = fmaf(gr[k], Wgg[k * GDIM + j], s);
    const float* pr = parts + (size_t)g * dout;
    for (int k = 0; k < dout; ++k) s = fmaf(pr[k], Wng[k * GDIM + j], s);
    out[g * GDIM + j] = s;
}

// ---------------- final sigmoid ----------------
__global__ void sigmoid_kernel(const float* __restrict__ h, float* __restrict__ out, int total4) {
    int idx = blockIdx.x * blockDim.x + threadIdx.x;
    if (idx >= total4) return;
    float4 v = *(const float4*)(h + (size_t)idx * 4);
    float4 o;
    o.x = 1.0f / (1.0f + expf(-v.x));
    o.y = 1.0f / (1.0f + expf(-v.y));
    o.z = 1.0f / (1.0f + expf(-v.z));
    o.w = 1.0f / (1.0f + expf(-v.w));
    *(float4*)(out + (size_t)idx * 4) = o;
}

extern "C" void kernel_launch(void* const* d_in, const int* in_sizes, int n_in,
                              void* d_out, int out_size, void* d_ws, size_t ws_size,
                              hipStream_t stream) {
    const float* x         = (const float*)d_in[0];
    const int*   ei        = (const int*)d_in[1];
    const int*   ga        = (const int*)d_in[2];
    const float* glob_init = (const float*)d_in[3];

    const int n = in_sizes[0] / 128;   // 50000
    const int E = in_sizes[1] / 2;     // 400000
    const int* row = ei;               // sources
    const int* col = ei + E;           // targets

    float* ws = (float*)d_ws;
    size_t off = 0;
    auto alloc = [&](size_t cnt) { float* p = ws + off; off += cnt; return p; };
    float* tmp   = alloc((size_t)n * 256);
    float* hbuf  = alloc((size_t)n * 256);
    float* dinv  = alloc((size_t)n);
    float* gn    = alloc((size_t)NG * 256);
    float* pp    = alloc((size_t)NG * 16 * 256);
    float* parts = alloc((size_t)NG * 256);
    float* globA = alloc((size_t)NG * GDIM);
    float* globB = alloc((size_t)NG * GDIM);
    int* cnt    = (int*)alloc((size_t)n);
    int* startA = (int*)alloc((size_t)n + 1);
    int* cursor = (int*)alloc((size_t)n);
    int* esrc   = (int*)alloc((size_t)E);
    (void)ws_size; (void)n_in; (void)out_size;

    // ---- build incoming-edge CSR (once) ----
    zero_int_kernel<<<(n + 255) / 256, 256, 0, stream>>>(cnt, n);
    count_kernel<<<(E + 255) / 256, 256, 0, stream>>>(col, cnt, E);
    dinv_kernel<<<(n + 255) / 256, 256, 0, stream>>>(cnt, dinv, n);
    scan_kernel<<<1, 1024, 0, stream>>>(cnt, startA, n);
    copy_int_kernel<<<(n + 255) / 256, 256, 0, stream>>>(startA, cursor, n);
    fill_kernel<<<(E + 255) / 256, 256, 0, stream>>>(row, col, cursor, esrc, E);

    glob_tile_kernel<<<NG, GDIM, 0, stream>>>(glob_init, globA);

    const float* hin = x;
    float* gcur = globA;
    float* gnext = globB;
    int K = 128;
    for (int li = 0; li < 3; ++li) {
        const float* Wnn = (const float*)d_in[4 + li * 8 + 0];
        const float* bnn = (const float*)d_in[4 + li * 8 + 1];
        const float* Wgn = (const float*)d_in[4 + li * 8 + 2];
        const float* bgn = (const float*)d_in[4 + li * 8 + 3];
        const float* Wgg = (const float*)d_in[4 + li * 8 + 4];
        const float* bgg = (const float*)d_in[4 + li * 8 + 5];
        const float* Wng = (const float*)d_in[4 + li * 8 + 6];
        const float* bng = (const float*)d_in[4 + li * 8 + 7];
        const int dout = (li == 2) ? 64 : 256;

        gn_kernel<<<NG, dout, 0, stream>>>(gcur, Wgn, bgn, gn, dout);

        dim3 ggrid((n + 63) / 64, dout / 64);
        gemm_kernel<<<ggrid, 256, 0, stream>>>(hin, Wnn, bnn, gn, ga, tmp, n, K, dout,
                                               li > 0 ? 1 : 0);

        if (dout == 256) {
            gather_kernel<256><<<((size_t)n * 64 + 255) / 256, 256, 0, stream>>>(
                tmp, hbuf, startA, esrc, dinv, n);
        } else {
            gather_kernel<64><<<((size_t)n * 16 + 255) / 256, 256, 0, stream>>>(
                tmp, hbuf, startA, esrc, dinv, n);
        }

        if (li < 2) {   // layer-2 glob update is dead code w.r.t. the output
            dim3 pgrid(NG, 16);
            parts_partial_kernel<<<pgrid, 256, 0, stream>>>(hbuf, ga, pp, n, dout);
            parts_reduce_kernel<<<NG, dout, 0, stream>>>(pp, parts, dout, 16);
            glob_update_kernel<<<NG, GDIM, 0, stream>>>(gcur, Wgg, bgg, parts, Wng, bng, gnext, dout);
            float* t = gcur; gcur = gnext; gnext = t;
        }
        hin = hbuf;
        K = dout;
    }

    sigmoid_kernel<<<((size_t)n * 64 / 4 + 255) / 256, 256, 0, stream>>>(hbuf, (float*)d_out,
                                                                         n * 64 / 4);
}

// Round 3
// 593.489 us; speedup vs baseline: 5.8069x; 1.1583x over previous
//
#include <hip/hip_runtime.h>
#include <math.h>
#include <float.h>

#define NG 64
#define GDIM 128

typedef short bf16x8 __attribute__((ext_vector_type(8)));
typedef float f32x4 __attribute__((ext_vector_type(4)));

__device__ inline unsigned short f2b(float f) {
    unsigned u = __builtin_bit_cast(unsigned, f);
    unsigned r = u + 0x7FFFu + ((u >> 16) & 1u);
    return (unsigned short)(r >> 16);
}
__device__ inline float b2f(unsigned short b) {
    unsigned u = ((unsigned)b) << 16;
    return __builtin_bit_cast(float, u);
}

// ---------------- CSR build ----------------
__global__ void zero_int_kernel(int* p, int n) {
    int i = blockIdx.x * blockDim.x + threadIdx.x;
    if (i < n) p[i] = 0;
}
__global__ void count_kernel(const int* __restrict__ col, int* cnt, int E) {
    int i = blockIdx.x * blockDim.x + threadIdx.x;
    if (i < E) atomicAdd(&cnt[col[i]], 1);
}
__global__ void dinv_kernel(const int* __restrict__ cnt, float* dinv, int n) {
    int i = blockIdx.x * blockDim.x + threadIdx.x;
    if (i < n) dinv[i] = rsqrtf((float)cnt[i] + 1.0f);
}
__global__ __launch_bounds__(1024) void scan_kernel(const int* __restrict__ cnt,
                                                    int* __restrict__ start, int n) {
    __shared__ int buf[1024];
    int carry = 0;
    for (int base = 0; base < n; base += 1024) {
        int i = base + threadIdx.x;
        int v = (i < n) ? cnt[i] : 0;
        buf[threadIdx.x] = v;
        __syncthreads();
        #pragma unroll
        for (int off = 1; off < 1024; off <<= 1) {
            int t = (threadIdx.x >= off) ? buf[threadIdx.x - off] : 0;
            __syncthreads();
            buf[threadIdx.x] += t;
            __syncthreads();
        }
        if (i < n) start[i + 1] = carry + buf[threadIdx.x];
        carry += buf[1023];
        __syncthreads();
    }
    if (threadIdx.x == 0) start[0] = 0;
}
__global__ void copy_int_kernel(const int* __restrict__ a, int* b, int n) {
    int i = blockIdx.x * blockDim.x + threadIdx.x;
    if (i < n) b[i] = a[i];
}
__global__ void fill_kernel(const int* __restrict__ row, const int* __restrict__ col,
                            int* cursor, int* __restrict__ esrc, int E) {
    int e = blockIdx.x * blockDim.x + threadIdx.x;
    if (e >= E) return;
    int c = col[e];
    int p = atomicAdd(&cursor[c], 1);
    esrc[p] = row[e];
}

// ---------------- small fp32 helpers ----------------
__global__ void glob_tile_kernel(const float* __restrict__ gi, float* glob) {
    glob[blockIdx.x * GDIM + threadIdx.x] = gi[threadIdx.x];
}
__global__ void gn_kernel(const float* __restrict__ glob, const float* __restrict__ Wgn,
                          const float* __restrict__ bgn, float* __restrict__ gn, int dout) {
    int g = blockIdx.x, j = threadIdx.x;
    float s = bgn[j];
    const float* gr = glob + g * GDIM;
    for (int k = 0; k < GDIM; ++k) s = fmaf(gr[k], Wgn[k * dout + j], s);
    gn[g * dout + j] = s;
}

// ---------------- x -> bf16 ----------------
__global__ void cvtx_kernel(const float* __restrict__ x, unsigned short* __restrict__ xb,
                            int total4) {
    int i = blockIdx.x * blockDim.x + threadIdx.x;
    if (i >= total4) return;
    float4 v = ((const float4*)x)[i];
    ushort4 o;
    o.x = f2b(v.x); o.y = f2b(v.y); o.z = f2b(v.z); o.w = f2b(v.w);
    ((ushort4*)xb)[i] = o;
}

// ---------------- W [K][DOUT] fp32 -> Wt [DOUT][K] bf16 ----------------
__global__ void wtrans_kernel(const float* __restrict__ W, unsigned short* __restrict__ Wt,
                              int K, int DOUT) {
    __shared__ float t[32][33];
    int k0 = blockIdx.x * 32, c0 = blockIdx.y * 32;
    int tx = threadIdx.x, ty = threadIdx.y;   // 32 x 8
    #pragma unroll
    for (int i = 0; i < 4; ++i)
        t[ty + i * 8][tx] = W[(size_t)(k0 + ty + i * 8) * DOUT + c0 + tx];
    __syncthreads();
    #pragma unroll
    for (int i = 0; i < 4; ++i)
        Wt[(size_t)(c0 + ty + i * 8) * K + k0 + tx] = f2b(t[tx][ty + i * 8]);
}

// ---------------- MFMA GEMM: C = relu?(A) @ Wt^T + bias + gn[ga] ----------------
// A [N][K] bf16, Wt [BN][K] bf16 (pre-transposed), C [N][BN] fp32. BK=32.
// 4 waves; wave grid (BM/64) x (BN/64); each wave: 4x4 frags of 16x16.
template <int BM, int BN>
__global__ __launch_bounds__(256) void mfma_gemm_kernel(
    const unsigned short* __restrict__ A, const unsigned short* __restrict__ Wt,
    const float* __restrict__ bias, const float* __restrict__ gn,
    const int* __restrict__ ga, float* __restrict__ C,
    int N, int K, int relu)
{
    __shared__ unsigned short Alds[BM * 32];
    __shared__ unsigned short Blds[BN * 32];
    int tid = threadIdx.x;
    int lane = tid & 63, wave = tid >> 6;
    constexpr int WN = BN / 64;
    int wm = wave / WN, wn = wave % WN;
    int row0 = blockIdx.x * BM;
    f32x4 acc[4][4];
    #pragma unroll
    for (int i = 0; i < 4; ++i)
        #pragma unroll
        for (int j = 0; j < 4; ++j) acc[i][j] = (f32x4){0.f, 0.f, 0.f, 0.f};

    for (int k0 = 0; k0 < K; k0 += 32) {
        // stage A: slot s -> (mf = s>>6, kg = (s>>4)&3, r = s&15), 8 bf16 each
        #pragma unroll
        for (int i = 0; i < BM / 64; ++i) {
            int s = tid + i * 256;
            int mf = s >> 6, kg = (s >> 4) & 3, r = s & 15;
            int grow = row0 + mf * 16 + r;
            int4 v = (int4){0, 0, 0, 0};
            if (grow < N) v = *(const int4*)(A + (size_t)grow * K + k0 + kg * 8);
            if (relu) {
                unsigned short* p = (unsigned short*)&v;
                #pragma unroll
                for (int q = 0; q < 8; ++q) p[q] = (p[q] & 0x8000) ? (unsigned short)0 : p[q];
            }
            *(int4*)(Alds + (size_t)s * 8) = v;
        }
        // stage B
        #pragma unroll
        for (int i = 0; i < BN / 64; ++i) {
            int s = tid + i * 256;
            int nf = s >> 6, kg = (s >> 4) & 3, c = s & 15;
            int col = nf * 16 + c;
            int4 v = *(const int4*)(Wt + (size_t)col * K + k0 + kg * 8);
            *(int4*)(Blds + (size_t)s * 8) = v;
        }
        __syncthreads();
        bf16x8 af[4], bfr[4];
        #pragma unroll
        for (int m = 0; m < 4; ++m)
            af[m] = *(const bf16x8*)(Alds + (size_t)(((wm * 4 + m) * 4 + (lane >> 4)) * 16 + (lane & 15)) * 8);
        #pragma unroll
        for (int nn = 0; nn < 4; ++nn)
            bfr[nn] = *(const bf16x8*)(Blds + (size_t)(((wn * 4 + nn) * 4 + (lane >> 4)) * 16 + (lane & 15)) * 8);
        #pragma unroll
        for (int m = 0; m < 4; ++m)
            #pragma unroll
            for (int nn = 0; nn < 4; ++nn)
                acc[m][nn] = __builtin_amdgcn_mfma_f32_16x16x32_bf16(af[m], bfr[nn], acc[m][nn], 0, 0, 0);
        __syncthreads();
    }

    int cbase = lane & 15;
    float bb[4];
    #pragma unroll
    for (int nn = 0; nn < 4; ++nn) bb[nn] = bias[(wn * 4 + nn) * 16 + cbase];
    #pragma unroll
    for (int m = 0; m < 4; ++m) {
        int rb = row0 + (wm * 4 + m) * 16 + (lane >> 4) * 4;
        #pragma unroll
        for (int reg = 0; reg < 4; ++reg) {
            int r = rb + reg;
            if (r < N) {
                int g = ga[r];
                const float* gnr = gn + (size_t)g * BN;
                #pragma unroll
                for (int nn = 0; nn < 4; ++nn) {
                    int col = (wn * 4 + nn) * 16 + cbase;
                    C[(size_t)r * BN + col] = acc[m][nn][reg] + bb[nn] + gnr[col];
                }
            }
        }
    }
}

// ---------------- CSR gather; MODE 0: bf16 out, MODE 1: fp32 sigmoid out ----------------
template <int DOUT, int MODE>
__global__ void gather_kernel(const float* __restrict__ tmp, void* __restrict__ outp,
                              const int* __restrict__ start, const int* __restrict__ esrc,
                              const float* __restrict__ dinv, int n) {
    constexpr int LPN = DOUT / 4;
    int t = blockIdx.x * blockDim.x + threadIdx.x;
    int node = t / LPN;
    if (node >= n) return;
    int lane = t % LPN;
    float dc = dinv[node];
    float4 v = *(const float4*)(tmp + (size_t)node * DOUT + lane * 4);
    float s0 = dc * dc;
    float ax = s0 * v.x, ay = s0 * v.y, az = s0 * v.z, aw = s0 * v.w;
    int a = start[node], b = start[node + 1];
    for (int j = a; j < b; ++j) {
        int r = esrc[j];
        float nrm = dc * dinv[r];
        float4 u = *(const float4*)(tmp + (size_t)r * DOUT + lane * 4);
        ax = fmaf(nrm, u.x, ax);
        ay = fmaf(nrm, u.y, ay);
        az = fmaf(nrm, u.z, az);
        aw = fmaf(nrm, u.w, aw);
    }
    if (MODE == 0) {
        ushort4 o;
        o.x = f2b(ax); o.y = f2b(ay); o.z = f2b(az); o.w = f2b(aw);
        ((ushort4*)outp)[(size_t)node * LPN + lane] = o;
    } else {
        float4 o;
        o.x = 1.0f / (1.0f + expf(-ax));
        o.y = 1.0f / (1.0f + expf(-ay));
        o.z = 1.0f / (1.0f + expf(-az));
        o.w = 1.0f / (1.0f + expf(-aw));
        ((float4*)outp)[(size_t)node * LPN + lane] = o;
    }
}

// ---------------- per-graph max on bf16 h ----------------
__global__ void parts_partial_kernel(const unsigned short* __restrict__ h,
                                     const int* __restrict__ ga,
                                     float* __restrict__ pp, int n, int dout) {
    int g = blockIdx.x, ch = blockIdx.y, nch = gridDim.y;
    int lo = 0, hi = n;
    while (lo < hi) { int m = (lo + hi) >> 1; if (ga[m] < g) lo = m + 1; else hi = m; }
    int s = lo;
    lo = s; hi = n;
    while (lo < hi) { int m = (lo + hi) >> 1; if (ga[m] <= g) lo = m + 1; else hi = m; }
    int epos = lo;
    int cnt = epos - s;
    int per = (cnt + nch - 1) / nch;
    int a = s + ch * per;
    int b = min(epos, a + per);
    for (int j = threadIdx.x; j < dout; j += blockDim.x) {
        float m = -INFINITY;
        for (int i = a; i < b; ++i) m = fmaxf(m, b2f(h[(size_t)i * dout + j]));
        pp[((size_t)g * nch + ch) * dout + j] = m;
    }
}
__global__ void parts_reduce_kernel(const float* __restrict__ pp, float* __restrict__ parts,
                                    int dout, int nch) {
    int g = blockIdx.x, j = threadIdx.x;
    float m = -INFINITY;
    for (int c = 0; c < nch; ++c) m = fmaxf(m, pp[((size_t)g * nch + c) * dout + j]);
    parts[g * dout + j] = m;
}
__global__ void glob_update_kernel(const float* __restrict__ glob, const float* __restrict__ Wgg,
                                   const float* __restrict__ bgg, const float* __restrict__ parts,
                                   const float* __restrict__ Wng, const float* __restrict__ bng,
                                   float* __restrict__ out, int dout) {
    int g = blockIdx.x, j = threadIdx.x;
    float s = bgg[j] + bng[j];
    const float* gr = glob + g * GDIM;
    for (int k = 0; k < GDIM; ++k) s = fmaf(gr[k], Wgg[k * GDIM + j], s);
    const float* pr = parts + (size_t)g * dout;
    for (int k = 0; k < dout; ++k) s = fmaf(pr[k], Wng[k * GDIM + j], s);
    out[g * GDIM + j] = s;
}

extern "C" void kernel_launch(void* const* d_in, const int* in_sizes, int n_in,
                              void* d_out, int out_size, void* d_ws, size_t ws_size,
                              hipStream_t stream) {
    const float* x         = (const float*)d_in[0];
    const int*   ei        = (const int*)d_in[1];
    const int*   ga        = (const int*)d_in[2];
    const float* glob_init = (const float*)d_in[3];

    const int n = in_sizes[0] / 128;   // 50000
    const int E = in_sizes[1] / 2;     // 400000
    const int* row = ei;               // sources
    const int* col = ei + E;           // targets

    float* ws = (float*)d_ws;
    size_t off = 0;
    auto alloc = [&](size_t cnt) { float* p = ws + off; off += cnt; return p; };
    float* tmp            = alloc((size_t)n * 256);            // fp32 conv pre-agg
    unsigned short* hb    = (unsigned short*)alloc((size_t)n * 128);  // bf16 h [N][256]
    unsigned short* xb    = (unsigned short*)alloc((size_t)n * 64);   // bf16 x [N][128]
    unsigned short* Wt    = (unsigned short*)alloc((size_t)32768);    // bf16 [DOUT][K] max 256x256
    float* dinv  = alloc((size_t)n);
    float* gnbuf = alloc((size_t)NG * 256);
    float* pp    = alloc((size_t)NG * 16 * 256);
    float* parts = alloc((size_t)NG * 256);
    float* globA = alloc((size_t)NG * GDIM);
    float* globB = alloc((size_t)NG * GDIM);
    int* cnt    = (int*)alloc((size_t)n);
    int* startA = (int*)alloc((size_t)n + 1);
    int* cursor = (int*)alloc((size_t)n);
    int* esrc   = (int*)alloc((size_t)E);
    (void)ws_size; (void)n_in; (void)out_size;

    // ---- CSR build ----
    zero_int_kernel<<<(n + 255) / 256, 256, 0, stream>>>(cnt, n);
    count_kernel<<<(E + 255) / 256, 256, 0, stream>>>(col, cnt, E);
    dinv_kernel<<<(n + 255) / 256, 256, 0, stream>>>(cnt, dinv, n);
    scan_kernel<<<1, 1024, 0, stream>>>(cnt, startA, n);
    copy_int_kernel<<<(n + 255) / 256, 256, 0, stream>>>(startA, cursor, n);
    fill_kernel<<<(E + 255) / 256, 256, 0, stream>>>(row, col, cursor, esrc, E);

    glob_tile_kernel<<<NG, GDIM, 0, stream>>>(glob_init, globA);
    cvtx_kernel<<<((size_t)n * 32 + 255) / 256, 256, 0, stream>>>(x, xb, n * 32);

    float* gcur = globA;
    float* gnext = globB;
    int K = 128;
    for (int li = 0; li < 3; ++li) {
        const float* Wnn = (const float*)d_in[4 + li * 8 + 0];
        const float* bnn = (const float*)d_in[4 + li * 8 + 1];
        const float* Wgn = (const float*)d_in[4 + li * 8 + 2];
        const float* bgn = (const float*)d_in[4 + li * 8 + 3];
        const float* Wgg = (const float*)d_in[4 + li * 8 + 4];
        const float* bgg = (const float*)d_in[4 + li * 8 + 5];
        const float* Wng = (const float*)d_in[4 + li * 8 + 6];
        const float* bng = (const float*)d_in[4 + li * 8 + 7];
        const int dout = (li == 2) ? 64 : 256;

        dim3 wtg(K / 32, dout / 32);
        wtrans_kernel<<<wtg, dim3(32, 8), 0, stream>>>(Wnn, Wt, K, dout);
        gn_kernel<<<NG, dout, 0, stream>>>(gcur, Wgn, bgn, gnbuf, dout);

        if (li == 0) {
            mfma_gemm_kernel<64, 256><<<(n + 63) / 64, 256, 0, stream>>>(
                xb, Wt, bnn, gnbuf, ga, tmp, n, 128, 0);
        } else if (li == 1) {
            mfma_gemm_kernel<64, 256><<<(n + 63) / 64, 256, 0, stream>>>(
                hb, Wt, bnn, gnbuf, ga, tmp, n, 256, 1);
        } else {
            mfma_gemm_kernel<256, 64><<<(n + 255) / 256, 256, 0, stream>>>(
                hb, Wt, bnn, gnbuf, ga, tmp, n, 256, 1);
        }

        if (li < 2) {
            gather_kernel<256, 0><<<((size_t)n * 64 + 255) / 256, 256, 0, stream>>>(
                tmp, hb, startA, esrc, dinv, n);
            dim3 pgrid(NG, 16);
            parts_partial_kernel<<<pgrid, 256, 0, stream>>>(hb, ga, pp, n, dout);
            parts_reduce_kernel<<<NG, dout, 0, stream>>>(pp, parts, dout, 16);
            glob_update_kernel<<<NG, GDIM, 0, stream>>>(gcur, Wgg, bgg, parts, Wng, bng, gnext, dout);
            float* t = gcur; gcur = gnext; gnext = t;
        } else {
            gather_kernel<64, 1><<<((size_t)n * 16 + 255) / 256, 256, 0, stream>>>(
                tmp, d_out, startA, esrc, dinv, n);
        }
        K = dout;
    }
}

// Round 4
// 428.702 us; speedup vs baseline: 8.0390x; 1.3844x over previous
//
#include <hip/hip_runtime.h>
#include <math.h>
#include <float.h>

#define NG 64
#define GDIM 128

typedef short bf16x8 __attribute__((ext_vector_type(8)));
typedef float f32x4 __attribute__((ext_vector_type(4)));

__device__ inline unsigned short f2b(float f) {
    unsigned u = __builtin_bit_cast(unsigned, f);
    unsigned r = u + 0x7FFFu + ((u >> 16) & 1u);
    return (unsigned short)(r >> 16);
}
__device__ inline float b2f(unsigned short b) {
    unsigned u = ((unsigned)b) << 16;
    return __builtin_bit_cast(float, u);
}

// ---------------- CSR build ----------------
__global__ void zero_int_kernel(int* p, int n) {
    int i = blockIdx.x * blockDim.x + threadIdx.x;
    if (i < n) p[i] = 0;
}
__global__ void count_kernel(const int* __restrict__ col, int* cnt, int E) {
    int i = blockIdx.x * blockDim.x + threadIdx.x;
    if (i < E) atomicAdd(&cnt[col[i]], 1);
}
__global__ void dinv_kernel(const int* __restrict__ cnt, float* dinv, int n) {
    int i = blockIdx.x * blockDim.x + threadIdx.x;
    if (i < n) dinv[i] = rsqrtf((float)cnt[i] + 1.0f);
}

// ---- 3-phase hierarchical exclusive scan over cnt[n] -> start[n+1] ----
#define SCAN_BS 256
__global__ void scan_partial_kernel(const int* __restrict__ cnt, int* __restrict__ bsum, int n) {
    __shared__ int red[SCAN_BS];
    int i = blockIdx.x * SCAN_BS + threadIdx.x;
    red[threadIdx.x] = (i < n) ? cnt[i] : 0;
    __syncthreads();
    #pragma unroll
    for (int off = SCAN_BS / 2; off > 0; off >>= 1) {
        if (threadIdx.x < off) red[threadIdx.x] += red[threadIdx.x + off];
        __syncthreads();
    }
    if (threadIdx.x == 0) bsum[blockIdx.x] = red[0];
}
__global__ __launch_bounds__(SCAN_BS) void scan_bsum_kernel(int* bsum, int nb) {
    __shared__ int buf[SCAN_BS];
    int t = threadIdx.x;
    buf[t] = (t < nb) ? bsum[t] : 0;
    __syncthreads();
    #pragma unroll
    for (int off = 1; off < SCAN_BS; off <<= 1) {
        int v = (t >= off) ? buf[t - off] : 0;
        __syncthreads();
        buf[t] += v;
        __syncthreads();
    }
    int ex = (t == 0) ? 0 : buf[t - 1];
    if (t < nb) bsum[t] = ex;
}
__global__ void scan_final_kernel(const int* __restrict__ cnt, const int* __restrict__ bsum,
                                  int* __restrict__ start, int n) {
    __shared__ int buf[SCAN_BS];
    int b = blockIdx.x, t = threadIdx.x;
    int i = b * SCAN_BS + t;
    buf[t] = (i < n) ? cnt[i] : 0;
    __syncthreads();
    #pragma unroll
    for (int off = 1; off < SCAN_BS; off <<= 1) {
        int v = (t >= off) ? buf[t - off] : 0;
        __syncthreads();
        buf[t] += v;
        __syncthreads();
    }
    if (i < n) start[i + 1] = bsum[b] + buf[t];
    if (i == 0) start[0] = 0;
}

__global__ void copy_int_kernel(const int* __restrict__ a, int* b, int n) {
    int i = blockIdx.x * blockDim.x + threadIdx.x;
    if (i < n) b[i] = a[i];
}
__global__ void fill_kernel(const int* __restrict__ row, const int* __restrict__ col,
                            int* cursor, int* __restrict__ esrc, int E) {
    int e = blockIdx.x * blockDim.x + threadIdx.x;
    if (e >= E) return;
    int c = col[e];
    int p = atomicAdd(&cursor[c], 1);
    esrc[p] = row[e];
}

// ---------------- glob init ----------------
__global__ void glob_tile_kernel(const float* __restrict__ gi, float* glob) {
    glob[blockIdx.x * GDIM + threadIdx.x] = gi[threadIdx.x];
}

// ---------------- gn = glob @ Wgn + bgn : block per graph, k-split ----------------
template <int DOUT>
__global__ __launch_bounds__(1024) void gn_kernel(const float* __restrict__ glob,
                                                  const float* __restrict__ Wgn,
                                                  const float* __restrict__ bgn,
                                                  float* __restrict__ gn) {
    constexpr int Q = 1024 / DOUT;   // 4 (DOUT=256) or 16 (DOUT=64)
    constexpr int KS = GDIM / Q;     // 32 or 8
    __shared__ float gr[GDIM];
    __shared__ float red[Q][DOUT];
    int g = blockIdx.x, tid = threadIdx.x;
    if (tid < GDIM) gr[tid] = glob[g * GDIM + tid];
    __syncthreads();
    int j = tid % DOUT, q = tid / DOUT;
    float s = 0.f;
    #pragma unroll
    for (int k = 0; k < KS; ++k) {
        int kk = q * KS + k;
        s = fmaf(gr[kk], Wgn[(size_t)kk * DOUT + j], s);
    }
    red[q][j] = s;
    __syncthreads();
    if (q == 0) {
        float r = s + bgn[j];
        #pragma unroll
        for (int t = 1; t < Q; ++t) r += red[t][j];
        gn[(size_t)g * DOUT + j] = r;
    }
}

// ---------------- glob update: block per graph, 512 thr = 128 j x 4 kq ----------------
__global__ __launch_bounds__(512) void glob_update_kernel(
    const float* __restrict__ glob, const float* __restrict__ Wgg,
    const float* __restrict__ bgg, const float* __restrict__ parts,
    const float* __restrict__ Wng, const float* __restrict__ bng,
    float* __restrict__ out) {
    __shared__ float gr[GDIM];
    __shared__ float pr[256];
    __shared__ float red[4][GDIM];
    int g = blockIdx.x, tid = threadIdx.x;
    if (tid < GDIM) gr[tid] = glob[g * GDIM + tid];
    else if (tid < GDIM + 256) pr[tid - GDIM] = parts[(size_t)g * 256 + (tid - GDIM)];
    __syncthreads();
    int j = tid & 127, q = tid >> 7;
    float s = 0.f;
    #pragma unroll
    for (int k = 0; k < 32; ++k) {
        int kk = q * 32 + k;
        s = fmaf(gr[kk], Wgg[(size_t)kk * GDIM + j], s);
    }
    #pragma unroll
    for (int k = 0; k < 64; ++k) {
        int kk = q * 64 + k;
        s = fmaf(pr[kk], Wng[(size_t)kk * GDIM + j], s);
    }
    red[q][j] = s;
    __syncthreads();
    if (q == 0) {
        out[(size_t)g * GDIM + j] =
            red[0][j] + red[1][j] + red[2][j] + red[3][j] + bgg[j] + bng[j];
    }
}

// ---------------- x -> bf16 ----------------
__global__ void cvtx_kernel(const float* __restrict__ x, unsigned short* __restrict__ xb,
                            int total4) {
    int i = blockIdx.x * blockDim.x + threadIdx.x;
    if (i >= total4) return;
    float4 v = ((const float4*)x)[i];
    ushort4 o;
    o.x = f2b(v.x); o.y = f2b(v.y); o.z = f2b(v.z); o.w = f2b(v.w);
    ((ushort4*)xb)[i] = o;
}

// ---------------- W [K][DOUT] fp32 -> Wt [DOUT][K] bf16 ----------------
__global__ void wtrans_kernel(const float* __restrict__ W, unsigned short* __restrict__ Wt,
                              int K, int DOUT) {
    __shared__ float t[32][33];
    int k0 = blockIdx.x * 32, c0 = blockIdx.y * 32;
    int tx = threadIdx.x, ty = threadIdx.y;   // 32 x 8
    #pragma unroll
    for (int i = 0; i < 4; ++i)
        t[ty + i * 8][tx] = W[(size_t)(k0 + ty + i * 8) * DOUT + c0 + tx];
    __syncthreads();
    #pragma unroll
    for (int i = 0; i < 4; ++i)
        Wt[(size_t)(c0 + ty + i * 8) * K + k0 + tx] = f2b(t[tx][ty + i * 8]);
}

// ---------------- MFMA GEMM: C = relu?(A) @ Wt^T + bias + gn[ga] ----------------
template <int BM, int BN>
__global__ __launch_bounds__(256) void mfma_gemm_kernel(
    const unsigned short* __restrict__ A, const unsigned short* __restrict__ Wt,
    const float* __restrict__ bias, const float* __restrict__ gn,
    const int* __restrict__ ga, float* __restrict__ C,
    int N, int K, int relu)
{
    __shared__ unsigned short Alds[BM * 32];
    __shared__ unsigned short Blds[BN * 32];
    int tid = threadIdx.x;
    int lane = tid & 63, wave = tid >> 6;
    constexpr int WN = BN / 64;
    int wm = wave / WN, wn = wave % WN;
    int row0 = blockIdx.x * BM;
    f32x4 acc[4][4];
    #pragma unroll
    for (int i = 0; i < 4; ++i)
        #pragma unroll
        for (int j = 0; j < 4; ++j) acc[i][j] = (f32x4){0.f, 0.f, 0.f, 0.f};

    for (int k0 = 0; k0 < K; k0 += 32) {
        #pragma unroll
        for (int i = 0; i < BM / 64; ++i) {
            int s = tid + i * 256;
            int mf = s >> 6, kg = (s >> 4) & 3, r = s & 15;
            int grow = row0 + mf * 16 + r;
            int4 v = (int4){0, 0, 0, 0};
            if (grow < N) v = *(const int4*)(A + (size_t)grow * K + k0 + kg * 8);
            if (relu) {
                unsigned short* p = (unsigned short*)&v;
                #pragma unroll
                for (int q = 0; q < 8; ++q) p[q] = (p[q] & 0x8000) ? (unsigned short)0 : p[q];
            }
            *(int4*)(Alds + (size_t)s * 8) = v;
        }
        #pragma unroll
        for (int i = 0; i < BN / 64; ++i) {
            int s = tid + i * 256;
            int nf = s >> 6, kg = (s >> 4) & 3, c = s & 15;
            int col = nf * 16 + c;
            int4 v = *(const int4*)(Wt + (size_t)col * K + k0 + kg * 8);
            *(int4*)(Blds + (size_t)s * 8) = v;
        }
        __syncthreads();
        bf16x8 af[4], bfr[4];
        #pragma unroll
        for (int m = 0; m < 4; ++m)
            af[m] = *(const bf16x8*)(Alds + (size_t)(((wm * 4 + m) * 4 + (lane >> 4)) * 16 + (lane & 15)) * 8);
        #pragma unroll
        for (int nn = 0; nn < 4; ++nn)
            bfr[nn] = *(const bf16x8*)(Blds + (size_t)(((wn * 4 + nn) * 4 + (lane >> 4)) * 16 + (lane & 15)) * 8);
        #pragma unroll
        for (int m = 0; m < 4; ++m)
            #pragma unroll
            for (int nn = 0; nn < 4; ++nn)
                acc[m][nn] = __builtin_amdgcn_mfma_f32_16x16x32_bf16(af[m], bfr[nn], acc[m][nn], 0, 0, 0);
        __syncthreads();
    }

    int cbase = lane & 15;
    float bb[4];
    #pragma unroll
    for (int nn = 0; nn < 4; ++nn) bb[nn] = bias[(wn * 4 + nn) * 16 + cbase];
    #pragma unroll
    for (int m = 0; m < 4; ++m) {
        int rb = row0 + (wm * 4 + m) * 16 + (lane >> 4) * 4;
        #pragma unroll
        for (int reg = 0; reg < 4; ++reg) {
            int r = rb + reg;
            if (r < N) {
                int g = ga[r];
                const float* gnr = gn + (size_t)g * BN;
                #pragma unroll
                for (int nn = 0; nn < 4; ++nn) {
                    int col = (wn * 4 + nn) * 16 + cbase;
                    C[(size_t)r * BN + col] = acc[m][nn][reg] + bb[nn] + gnr[col];
                }
            }
        }
    }
}

// ---------------- CSR gather; MODE 0: bf16 out, MODE 1: fp32 sigmoid out ----------------
template <int DOUT, int MODE>
__global__ void gather_kernel(const float* __restrict__ tmp, void* __restrict__ outp,
                              const int* __restrict__ start, const int* __restrict__ esrc,
                              const float* __restrict__ dinv, int n) {
    constexpr int LPN = DOUT / 4;
    int t = blockIdx.x * blockDim.x + threadIdx.x;
    int node = t / LPN;
    if (node >= n) return;
    int lane = t % LPN;
    float dc = dinv[node];
    float4 v = *(const float4*)(tmp + (size_t)node * DOUT + lane * 4);
    float s0 = dc * dc;
    float ax = s0 * v.x, ay = s0 * v.y, az = s0 * v.z, aw = s0 * v.w;
    int a = start[node], b = start[node + 1];
    for (int j = a; j < b; ++j) {
        int r = esrc[j];
        float nrm = dc * dinv[r];
        float4 u = *(const float4*)(tmp + (size_t)r * DOUT + lane * 4);
        ax = fmaf(nrm, u.x, ax);
        ay = fmaf(nrm, u.y, ay);
        az = fmaf(nrm, u.z, az);
        aw = fmaf(nrm, u.w, aw);
    }
    if (MODE == 0) {
        ushort4 o;
        o.x = f2b(ax); o.y = f2b(ay); o.z = f2b(az); o.w = f2b(aw);
        ((ushort4*)outp)[(size_t)node * LPN + lane] = o;
    } else {
        float4 o;
        o.x = 1.0f / (1.0f + expf(-ax));
        o.y = 1.0f / (1.0f + expf(-ay));
        o.z = 1.0f / (1.0f + expf(-az));
        o.w = 1.0f / (1.0f + expf(-aw));
        ((float4*)outp)[(size_t)node * LPN + lane] = o;
    }
}

// ---------------- per-graph max on bf16 h ----------------
__global__ void parts_partial_kernel(const unsigned short* __restrict__ h,
                                     const int* __restrict__ ga,
                                     float* __restrict__ pp, int n, int dout) {
    int g = blockIdx.x, ch = blockIdx.y, nch = gridDim.y;
    int lo = 0, hi = n;
    while (lo < hi) { int m = (lo + hi) >> 1; if (ga[m] < g) lo = m + 1; else hi = m; }
    int s = lo;
    lo = s; hi = n;
    while (lo < hi) { int m = (lo + hi) >> 1; if (ga[m] <= g) lo = m + 1; else hi = m; }
    int epos = lo;
    int cnt = epos - s;
    int per = (cnt + nch - 1) / nch;
    int a = s + ch * per;
    int b = min(epos, a + per);
    for (int j = threadIdx.x; j < dout; j += blockDim.x) {
        float m = -INFINITY;
        for (int i = a; i < b; ++i) m = fmaxf(m, b2f(h[(size_t)i * dout + j]));
        pp[((size_t)g * nch + ch) * dout + j] = m;
    }
}
__global__ void parts_reduce_kernel(const float* __restrict__ pp, float* __restrict__ parts,
                                    int dout, int nch) {
    int g = blockIdx.x, j = threadIdx.x;
    float m = -INFINITY;
    for (int c = 0; c < nch; ++c) m = fmaxf(m, pp[((size_t)g * nch + c) * dout + j]);
    parts[g * dout + j] = m;
}

extern "C" void kernel_launch(void* const* d_in, const int* in_sizes, int n_in,
                              void* d_out, int out_size, void* d_ws, size_t ws_size,
                              hipStream_t stream) {
    const float* x         = (const float*)d_in[0];
    const int*   ei        = (const int*)d_in[1];
    const int*   ga        = (const int*)d_in[2];
    const float* glob_init = (const float*)d_in[3];

    const int n = in_sizes[0] / 128;   // 50000
    const int E = in_sizes[1] / 2;     // 400000
    const int* row = ei;               // sources
    const int* col = ei + E;           // targets

    float* ws = (float*)d_ws;
    size_t off = 0;
    auto alloc = [&](size_t cnt) { float* p = ws + off; off += cnt; return p; };
    float* tmp            = alloc((size_t)n * 256);
    unsigned short* hb    = (unsigned short*)alloc((size_t)n * 128);
    unsigned short* xb    = (unsigned short*)alloc((size_t)n * 64);
    unsigned short* Wt    = (unsigned short*)alloc((size_t)32768);
    float* dinv  = alloc((size_t)n);
    float* gnbuf = alloc((size_t)NG * 256);
    float* pp    = alloc((size_t)NG * 16 * 256);
    float* parts = alloc((size_t)NG * 256);
    float* globA = alloc((size_t)NG * GDIM);
    float* globB = alloc((size_t)NG * GDIM);
    int* cnt    = (int*)alloc((size_t)n);
    int* startA = (int*)alloc((size_t)n + 1);
    int* cursor = (int*)alloc((size_t)n);
    int* esrc   = (int*)alloc((size_t)E);
    int* bsum   = (int*)alloc((size_t)SCAN_BS);
    (void)ws_size; (void)n_in; (void)out_size;

    const int nb = (n + SCAN_BS - 1) / SCAN_BS;   // 196

    // ---- CSR build ----
    zero_int_kernel<<<(n + 255) / 256, 256, 0, stream>>>(cnt, n);
    count_kernel<<<(E + 255) / 256, 256, 0, stream>>>(col, cnt, E);
    dinv_kernel<<<(n + 255) / 256, 256, 0, stream>>>(cnt, dinv, n);
    scan_partial_kernel<<<nb, SCAN_BS, 0, stream>>>(cnt, bsum, n);
    scan_bsum_kernel<<<1, SCAN_BS, 0, stream>>>(bsum, nb);
    scan_final_kernel<<<nb, SCAN_BS, 0, stream>>>(cnt, bsum, startA, n);
    copy_int_kernel<<<(n + 255) / 256, 256, 0, stream>>>(startA, cursor, n);
    fill_kernel<<<(E + 255) / 256, 256, 0, stream>>>(row, col, cursor, esrc, E);

    glob_tile_kernel<<<NG, GDIM, 0, stream>>>(glob_init, globA);
    cvtx_kernel<<<((size_t)n * 32 + 255) / 256, 256, 0, stream>>>(x, xb, n * 32);

    float* gcur = globA;
    float* gnext = globB;
    int K = 128;
    for (int li = 0; li < 3; ++li) {
        const float* Wnn = (const float*)d_in[4 + li * 8 + 0];
        const float* bnn = (const float*)d_in[4 + li * 8 + 1];
        const float* Wgn = (const float*)d_in[4 + li * 8 + 2];
        const float* bgn = (const float*)d_in[4 + li * 8 + 3];
        const float* Wgg = (const float*)d_in[4 + li * 8 + 4];
        const float* bgg = (const float*)d_in[4 + li * 8 + 5];
        const float* Wng = (const float*)d_in[4 + li * 8 + 6];
        const float* bng = (const float*)d_in[4 + li * 8 + 7];
        const int dout = (li == 2) ? 64 : 256;

        dim3 wtg(K / 32, dout / 32);
        wtrans_kernel<<<wtg, dim3(32, 8), 0, stream>>>(Wnn, Wt, K, dout);
        if (dout == 256)
            gn_kernel<256><<<NG, 1024, 0, stream>>>(gcur, Wgn, bgn, gnbuf);
        else
            gn_kernel<64><<<NG, 1024, 0, stream>>>(gcur, Wgn, bgn, gnbuf);

        if (li == 0) {
            mfma_gemm_kernel<64, 256><<<(n + 63) / 64, 256, 0, stream>>>(
                xb, Wt, bnn, gnbuf, ga, tmp, n, 128, 0);
        } else if (li == 1) {
            mfma_gemm_kernel<64, 256><<<(n + 63) / 64, 256, 0, stream>>>(
                hb, Wt, bnn, gnbuf, ga, tmp, n, 256, 1);
        } else {
            mfma_gemm_kernel<256, 64><<<(n + 255) / 256, 256, 0, stream>>>(
                hb, Wt, bnn, gnbuf, ga, tmp, n, 256, 1);
        }

        if (li < 2) {
            gather_kernel<256, 0><<<((size_t)n * 64 + 255) / 256, 256, 0, stream>>>(
                tmp, hb, startA, esrc, dinv, n);
            dim3 pgrid(NG, 16);
            parts_partial_kernel<<<pgrid, 256, 0, stream>>>(hb, ga, pp, n, dout);
            parts_reduce_kernel<<<NG, dout, 0, stream>>>(pp, parts, dout, 16);
            glob_update_kernel<<<NG, 512, 0, stream>>>(gcur, Wgg, bgg, parts, Wng, bng, gnext);
            float* t = gcur; gcur = gnext; gnext = t;
        } else {
            gather_kernel<64, 1><<<((size_t)n * 16 + 255) / 256, 256, 0, stream>>>(
                tmp, d_out, startA, esrc, dinv, n);
        }
        K = dout;
    }
}